// Round 17
// baseline (243.353 us; speedup 1.0000x reference)
//
#include <hip/hip_runtime.h>
#include <hip/hip_bf16.h>

// ===== Problem constants =====
// B=8, N=1025, C=768, H=12, HD=64
constexpr int NTOK   = 1025;
constexpr int M      = 8 * NTOK;      // 8200 tokens
constexpr int MP     = 8448;          // 33 * 256 padded rows
constexpr int KDIM   = 768;
constexpr int NQKV   = 2304;
constexpr int NKVPAD = 1088;          // 17*64 padded kv length for vT
constexpr float SCALEL2 = 0.125f * 1.44269504f; // 64^-0.5 * log2(e), folded into K

using bf16x8 = __attribute__((ext_vector_type(8))) short;
using f32x4  = __attribute__((ext_vector_type(4))) float;

__device__ __forceinline__ f32x4 mfma_bf16(bf16x8 a, bf16x8 b, f32x4 c) {
  return __builtin_amdgcn_mfma_f32_16x16x32_bf16(a, b, c, 0, 0, 0);
}

__device__ __forceinline__ void gl16(const void* g, void* l) {
  __builtin_amdgcn_global_load_lds(
      (const __attribute__((address_space(1))) void*)g,
      (__attribute__((address_space(3))) void*)l, 16, 0, 0);
}

// counted vmcnt wait (T4): never drain to 0 in the main loop
template <int N> __device__ __forceinline__ void wait_vmcnt() {
  if constexpr (N == 0)
    asm volatile("s_waitcnt vmcnt(0)" ::: "memory");
  else if constexpr (N == 4)
    asm volatile("s_waitcnt vmcnt(4)" ::: "memory");
  else if constexpr (N == 6)
    asm volatile("s_waitcnt vmcnt(6)" ::: "memory");
}

// raw 2^x (args bounded by defer-max <= 8; -1e30 masks flush to 0)
__device__ __forceinline__ float exp2_raw(float x) {
  float r;
  asm("v_exp_f32 %0, %1" : "=v"(r) : "v"(x));
  return r;
}
// hardware-RNE f32->bf16 (1 op vs ~5-op software RNE)
__device__ __forceinline__ unsigned short cvt_bf16_u16(float x) {
  unsigned u;
  asm("v_cvt_pk_bf16_f32 %0, %1, %2" : "=v"(u) : "v"(x), "v"(x));
  return (unsigned short)(u & 0xffffu);
}
__device__ __forceinline__ __hip_bfloat16 cvt_bf16_raw(float x) {
  union { unsigned short s; __hip_bfloat16 b; } c;
  c.s = cvt_bf16_u16(x);
  return c.b;
}

// ===== Workspace layout (bytes), all 256-aligned =====
constexpr size_t SZ_X     = (size_t)MP * KDIM * 2;        // 12,976,128
constexpr size_t SZ_WQ    = (size_t)NQKV * KDIM * 2;      // 3,538,944
constexpr size_t SZ_PW    = (size_t)KDIM * KDIM * 2;      // 1,179,648
constexpr size_t SZ_QK    = (size_t)96 * NTOK * 64 * 2;   // 12,595,200
constexpr size_t SZ_VT    = (size_t)96 * 64 * NKVPAD * 2; // 13,369,344
constexpr size_t OFF_XHI  = 0;
constexpr size_t OFF_WQHI = OFF_XHI + SZ_X;
constexpr size_t OFF_PWHI = OFF_WQHI + SZ_WQ;
constexpr size_t OFF_Q    = OFF_PWHI + SZ_PW;
constexpr size_t OFF_K    = OFF_Q + SZ_QK;
constexpr size_t OFF_VT   = OFF_K + SZ_QK;
constexpr size_t OFF_AO   = OFF_VT + SZ_VT;
// total ~69 MB

// ===== K0: fused prep — x->bf16 (zero tail to MP rows), qkv_w->bf16,
// proj_w->bf16, vT pad-zero. One launch, float4/ushort4 vectorized. =====
constexpr int N4_X  = MP * KDIM / 4;          // 1,622,016
constexpr int N4_WQ = NQKV * KDIM / 4;        //   442,368
constexpr int N4_PW = KDIM * KDIM / 4;        //   147,456
constexpr int NPADC = NKVPAD - NTOK;          // 63
constexpr int N4_PAD = 96 * 64 * NPADC / 4;   //    96,768
constexpr int N4_TOT = N4_X + N4_WQ + N4_PW + N4_PAD; // 2,308,608 = 9018*256

__global__ void k_prep(const float* __restrict__ x, const float* __restrict__ qkvw,
                       const float* __restrict__ projw,
                       __hip_bfloat16* __restrict__ xhi,
                       __hip_bfloat16* __restrict__ wqhi,
                       __hip_bfloat16* __restrict__ pwhi,
                       __hip_bfloat16* __restrict__ vt) {
  const int u = blockIdx.x * 256 + threadIdx.x;
  if (u < N4_X) {
    const int i = u * 4;
    ushort4 o = {0, 0, 0, 0};
    if (i < M * KDIM) {
      const float4 v = *(const float4*)(x + i);
      o = ushort4{cvt_bf16_u16(v.x), cvt_bf16_u16(v.y), cvt_bf16_u16(v.z),
                  cvt_bf16_u16(v.w)};
    }
    *(ushort4*)((unsigned short*)xhi + i) = o;
  } else if (u < N4_X + N4_WQ) {
    const int i = (u - N4_X) * 4;
    const float4 v = *(const float4*)(qkvw + i);
    *(ushort4*)((unsigned short*)wqhi + i) = ushort4{
        cvt_bf16_u16(v.x), cvt_bf16_u16(v.y), cvt_bf16_u16(v.z), cvt_bf16_u16(v.w)};
  } else if (u < N4_X + N4_WQ + N4_PW) {
    const int i = (u - N4_X - N4_WQ) * 4;
    const float4 v = *(const float4*)(projw + i);
    *(ushort4*)((unsigned short*)pwhi + i) = ushort4{
        cvt_bf16_u16(v.x), cvt_bf16_u16(v.y), cvt_bf16_u16(v.z), cvt_bf16_u16(v.w)};
  } else {
    const int e0 = (u - N4_X - N4_WQ - N4_PW) * 4;
#pragma unroll
    for (int k = 0; k < 4; ++k) {
      const int e = e0 + k;
      const int r = e / NPADC;
      const int c = NTOK + (e - r * NPADC);
      vt[(size_t)r * NKVPAD + c] = __float2bfloat16(0.0f);
    }
  }
}

// ===== K1: QKV GEMM — 256x256 tile, 8 waves (2m x 4n), BK=32,
// counted-vmcnt 3-buffer pipeline (R12's proven hazard structure, bigger
// constants: 32 MFMA + 12 ds_read_b128 + 4 gl16 per wave-step). LDS 3 bufs
// x (A 16KB + B 16KB) = 96KB -> 1 block/CU, 8 waves = 2 waves/SIMD (VGPR
// <=256 suffices in this regime; multi-block TLP not needed — the counted
// pipeline provides the overlap). acc[8][4] = 128 VGPR, fully static.
// Swizzle: chunk c -> row=c>>2, slot=(c&3)^((row>>1)&3) (linear gl16 dest +
// pre-swizzled source; fragment ph=(q4^((row>>1)&3))<<4, conflict-free).
// Grid 297 = 9 cols x 33 row-panels, bijective XCD-chunk remap.
// Epilogue: bias + RoPE (pair = acc[mt][nt^2], cols within wave's 64-span)
// -> q, k(pre-scaled by SCALEL2), vT.
template <int NBX>
__global__ __launch_bounds__(512) void k_gemm_qkv(
    const __hip_bfloat16* __restrict__ A, const __hip_bfloat16* __restrict__ B,
    const float* __restrict__ bias, const float* __restrict__ sinp,
    const float* __restrict__ cosp, __hip_bfloat16* __restrict__ o_q,
    __hip_bfloat16* __restrict__ o_k, __hip_bfloat16* __restrict__ o_vt) {
  const int tid = threadIdx.x;
  const int w = tid >> 6, lane = tid & 63;
  const int wm = w >> 2, wn = w & 3; // 2m x 4n wave grid
  const int l15 = lane & 15, q4 = lane >> 4;

  // bijective XCD-chunk remap (nwg = 297: qc=37, rc=1)
  const int nwg = gridDim.x;
  const int orig = blockIdx.x;
  const int qc = nwg >> 3, rc = nwg & 7;
  const int xcd = orig & 7, o8 = orig >> 3;
  const int wg =
      (xcd < rc ? xcd * (qc + 1) : rc * (qc + 1) + (xcd - rc) * qc) + o8;
  const int bx = wg % NBX, by = wg / NBX;
  const int mBase = by * 256, nBase = bx * 256;

  // 3 bufs x [A 256x32 (8192 el) | B 256x32 (8192 el)]
  __shared__ __hip_bfloat16 sm[3][16384];
  constexpr int OFFB = 16384; // byte offset of B tile within a buf

  const char* pA = (const char*)A + (size_t)mBase * 1536;
  const char* pB = (const char*)B + (size_t)nBase * 1536;

  // hoisted staging offsets: A 1024 chunks (2/thread), B 1024 chunks (2/thread)
  int sSrc[2], sDst[2];
#pragma unroll
  for (int i = 0; i < 2; ++i) {
    const int c = i * 512 + tid;
    const int row = c >> 2;
    sSrc[i] = row * 1536 + (((c & 3) ^ ((row >> 1) & 3)) << 4);
    sDst[i] = c << 4;
  }
  auto stage = [&](int kt, int buf) {
    const int kofs = kt * 64; // 32 bf16 along K per step
    char* base = (char*)&sm[buf][0];
#pragma unroll
    for (int i = 0; i < 2; ++i) {
      gl16(pA + sSrc[i] + kofs, base + sDst[i]);
      gl16(pB + sSrc[i] + kofs, base + OFFB + sDst[i]);
    }
  };

  // hoisted fragment byte offsets (row pitch 64B, swizzled 16B slot)
  int fA[8], fB[4];
#pragma unroll
  for (int f = 0; f < 8; ++f) {
    const int ra = wm * 128 + f * 16 + l15;
    fA[f] = ra * 64 + ((q4 ^ ((ra >> 1) & 3)) << 4);
  }
#pragma unroll
  for (int f = 0; f < 4; ++f) {
    const int rb = wn * 64 + f * 16 + l15;
    fB[f] = OFFB + rb * 64 + ((q4 ^ ((rb >> 1) & 3)) << 4);
  }

  f32x4 acc[8][4] = {};

  stage(0, 0);
  stage(1, 1); // depth-2 prologue: 8 loads/thread in flight

  constexpr int NKT = KDIM / 32; // 24
  for (int kt = 0; kt < NKT; ++kt) {
    if (kt < NKT - 1)
      wait_vmcnt<4>(); // tile kt landed; kt+1's 4 loads stay in flight
    else
      wait_vmcnt<0>();
    __builtin_amdgcn_s_barrier();
    if (kt + 2 < NKT) stage(kt + 2, (kt + 2) % 3);
    const char* s = (const char*)&sm[kt % 3][0];
    bf16x8 a[8], b[4];
#pragma unroll
    for (int f = 0; f < 8; ++f) a[f] = *(const bf16x8*)(s + fA[f]);
#pragma unroll
    for (int f = 0; f < 4; ++f) b[f] = *(const bf16x8*)(s + fB[f]);
    __builtin_amdgcn_s_setprio(1);
#pragma unroll
    for (int mt = 0; mt < 8; ++mt)
#pragma unroll
      for (int nt = 0; nt < 4; ++nt)
        acc[mt][nt] = mfma_bf16(a[mt], b[nt], acc[mt][nt]);
    __builtin_amdgcn_s_setprio(0);
  }

  // epilogue; C layout: col = lane&15, row = 4*(lane>>4)+j
#pragma unroll
  for (int mt = 0; mt < 8; ++mt)
#pragma unroll
    for (int j = 0; j < 4; ++j) {
      const int gm = mBase + wm * 128 + mt * 16 + q4 * 4 + j;
      if (gm >= M) continue;
      const int b = gm / NTOK;
      const int t = gm - b * NTOK;
#pragma unroll
      for (int nt = 0; nt < 4; ++nt) {
        const int gc = nBase + wn * 64 + nt * 16 + l15;
        float v = acc[mt][nt][j] + bias[gc];
        const int three = gc / 768;
        const int hd = gc - three * 768;
        const int h = hd >> 6, d = hd & 63;
        const int bh = b * 12 + h;
        if (three == 2) {
          o_vt[((size_t)bh * 64 + d) * NKVPAD + t] = __float2bfloat16(v);
        } else {
          if (t > 0) {
            const float pv = acc[mt][nt ^ 2][j] + bias[gc ^ 32];
            const int so = (t - 1) * 64 + d;
            v = v * cosp[so] + ((d < 32) ? -pv : pv) * sinp[so];
          }
          if (three == 0)
            o_q[((size_t)bh * NTOK + t) * 64 + d] = __float2bfloat16(v);
          else  // K: fold softmax scale * log2(e) here
            o_k[((size_t)bh * NTOK + t) * 64 + d] = __float2bfloat16(v * SCALEL2);
        }
      }
    }
}

// ===== K3: proj GEMM — 128x128, BK=32, NT=2 (w hi only; the w_lo term's
// contribution ~1e-3 absmax, well under budget), counted-vmcnt 3-buf
// (R12-QKV's exact proven form with the f32 epilogue). =====
template <int NBX>
__global__ __launch_bounds__(256) void k_gemm_proj(
    const __hip_bfloat16* __restrict__ Ain, const __hip_bfloat16* __restrict__ Bhi,
    const float* __restrict__ bias, float* __restrict__ o_f32) {
  const int tid = threadIdx.x;
  const int w = tid >> 6, lane = tid & 63;
  const int wm = w >> 1, wn = w & 1;
  const int l15 = lane & 15, q4 = lane >> 4;

  const int nwg = gridDim.x;
  const int orig = blockIdx.x;
  const int qc = nwg >> 3, rc = nwg & 7;
  const int xcd = orig & 7, o8 = orig >> 3;
  const int wg =
      (xcd < rc ? xcd * (qc + 1) : rc * (qc + 1) + (xcd - rc) * qc) + o8;
  const int bx = wg % NBX, by = wg / NBX;
  const int mBase = by * 128, nBase = bx * 128;

  __shared__ __hip_bfloat16 sm[3][2 * 4096]; // 3 bufs x (A 8KB + B 8KB)
  constexpr int OFFB = 8192;

  const char* p0 = (const char*)Ain + (size_t)mBase * (KDIM * 2);
  const char* p2 = (const char*)Bhi + (size_t)nBase * (KDIM * 2);

  const int slog = ((tid & 3) ^ ((tid >> 3) & 3)) << 4;
  const int ph = ((q4 ^ ((l15 >> 1) & 3)) << 4);

  auto stage = [&](int kt, int buf) {
    const int kofs = kt * 64;
    char* base = (char*)sm[buf];
#pragma unroll
    for (int i = 0; i < 2; ++i) {
      const int c = i * 256 + tid;
      const size_t rb = (size_t)(i * 64 + (tid >> 2)) * (KDIM * 2) + slog + kofs;
      gl16(p0 + rb, base + (size_t)c * 16);
      gl16(p2 + rb, base + OFFB + (size_t)c * 16);
    }
  };

  f32x4 acc[4][4] = {};

  stage(0, 0);
  stage(1, 1);

  constexpr int NKT = KDIM / 32; // 24
  for (int kt = 0; kt < NKT; ++kt) {
    if (kt < NKT - 1)
      wait_vmcnt<4>();
    else
      wait_vmcnt<0>();
    __builtin_amdgcn_s_barrier();
    if (kt + 2 < NKT) stage(kt + 2, (kt + 2) % 3);
    char* s0 = (char*)sm[kt % 3];
    char* s2 = s0 + OFFB;
    bf16x8 a0[4], b0[4];
#pragma unroll
    for (int mt = 0; mt < 4; ++mt) {
      const int r = wm * 64 + mt * 16 + l15;
      a0[mt] = *(const bf16x8*)(s0 + r * 64 + ph);
    }
#pragma unroll
    for (int nt = 0; nt < 4; ++nt) {
      const int r = wn * 64 + nt * 16 + l15;
      b0[nt] = *(const bf16x8*)(s2 + r * 64 + ph);
    }
    __builtin_amdgcn_s_setprio(1);
#pragma unroll
    for (int mt = 0; mt < 4; ++mt)
#pragma unroll
      for (int nt = 0; nt < 4; ++nt)
        acc[mt][nt] = mfma_bf16(a0[mt], b0[nt], acc[mt][nt]);
    __builtin_amdgcn_s_setprio(0);
  }

#pragma unroll
  for (int mt = 0; mt < 4; ++mt)
#pragma unroll
    for (int j = 0; j < 4; ++j) {
      const int gm = mBase + wm * 64 + mt * 16 + q4 * 4 + j;
      if (gm >= M) continue;
#pragma unroll
      for (int nt = 0; nt < 4; ++nt) {
        const int gc = nBase + wn * 64 + nt * 16 + l15;
        o_f32[(size_t)gm * 768 + gc] = acc[mt][nt][j] + bias[gc];
      }
    }
}

// ===== K2: flash attention, 4 waves x 32 q-rows, KV tiles of 64 =====
// (R12 form, unchanged.)
__global__ __launch_bounds__(256) void k_attn(
    const __hip_bfloat16* __restrict__ Q, const __hip_bfloat16* __restrict__ Kk,
    const __hip_bfloat16* __restrict__ VT, __hip_bfloat16* __restrict__ ao) {
  __shared__ __hip_bfloat16 Kt[3][64 * 64];
  __shared__ __hip_bfloat16 Vt[3][64 * 64];
  __shared__ __hip_bfloat16 Pl[4][32][72];
  const int tid = threadIdx.x, w = tid >> 6, lane = tid & 63;
  const int l15 = lane & 15, q4 = lane >> 4;
  const int id = blockIdx.x;
  const int xcd = id & 7, sub = id >> 3;
  const int hh = sub / 9;
  const int bh = xcd * 12 + hh;
  const int qb = (sub - hh * 9) * 128 + w * 32;
  const size_t qbase = (size_t)bh * NTOK * 64;
  const char* Kb = (const char*)(Kk + qbase);
  const char* Vb = (const char*)(VT + (size_t)bh * 64 * NKVPAD);

  int frag_off[2][4];
#pragma unroll
  for (int f = 0; f < 4; ++f) {
    const int row = f * 16 + l15;
#pragma unroll
    for (int ks = 0; ks < 2; ++ks)
      frag_off[ks][f] = row * 128 + (((ks * 4 + q4) ^ (row & 7)) << 4);
  }
  int stRow[2], sch16[2], stK[2], stV[2], ldsOff[2];
#pragma unroll
  for (int i = 0; i < 2; ++i) {
    const int c = i * 256 + tid;
    const int row = c >> 3;
    stRow[i] = row;
    sch16[i] = ((c & 7) ^ (row & 7)) << 4;
    stK[i] = row * 128 + sch16[i];
    stV[i] = row * (NKVPAD * 2) + sch16[i];
    ldsOff[i] = c * 16;
  }
  int pw_off[2][4], pa_off[2][2];
#pragma unroll
  for (int mt = 0; mt < 2; ++mt) {
#pragma unroll
    for (int j = 0; j < 4; ++j)
      pw_off[mt][j] = ((w * 32 + mt * 16 + q4 * 4 + j) * 72 + l15) * 2;
#pragma unroll
    for (int ks = 0; ks < 2; ++ks)
      pa_off[mt][ks] = ((w * 32 + mt * 16 + l15) * 72 + ks * 32 + q4 * 8) * 2;
  }
  char* Plc = (char*)&Pl[0][0][0];

  bf16x8 qa[2][2];
#pragma unroll
  for (int mt = 0; mt < 2; ++mt) {
    int t = qb + mt * 16 + l15;
    if (t > NTOK - 1) t = NTOK - 1;
#pragma unroll
    for (int ks = 0; ks < 2; ++ks)
      qa[mt][ks] = *(const bf16x8*)(Q + qbase + (size_t)t * 64 + ks * 32 + q4 * 8);
  }

  f32x4 accO[2][4] = {};
  float mrun[2][4], lpart[2][4];
#pragma unroll
  for (int mt = 0; mt < 2; ++mt)
#pragma unroll
    for (int j = 0; j < 4; ++j) {
      mrun[mt][j] = -1e30f;
      lpart[mt][j] = 0.0f;
    }

  auto stageKV = [&](int kt, int b) {
    const int kb0 = kt * 64;
#pragma unroll
    for (int i = 0; i < 2; ++i) {
      const char* srcK;
      if (kt == 16) {
        const int srow = min(kb0 + stRow[i], NTOK - 1);
        srcK = Kb + (size_t)srow * 128 + sch16[i];
      } else {
        srcK = Kb + (size_t)kb0 * 128 + stK[i];
      }
      gl16(srcK, (char*)&Kt[b][0] + ldsOff[i]);
      gl16(Vb + (size_t)kb0 * 2 + stV[i], (char*)&Vt[b][0] + ldsOff[i]);
    }
  };

  auto step = [&](int kt, int cur, bool last) {
    f32x4 s[2][4] = {};
    {
      const char* Kc = (const char*)&Kt[cur][0];
      bf16x8 kfr[2][4];
#pragma unroll
      for (int nt = 0; nt < 4; ++nt)
#pragma unroll
        for (int ks = 0; ks < 2; ++ks)
          kfr[ks][nt] = *(const bf16x8*)(Kc + frag_off[ks][nt]);
      __builtin_amdgcn_s_setprio(1);
#pragma unroll
      for (int mt = 0; mt < 2; ++mt)
#pragma unroll
        for (int nt = 0; nt < 4; ++nt)
#pragma unroll
          for (int ks = 0; ks < 2; ++ks)
            s[mt][nt] = mfma_bf16(qa[mt][ks], kfr[ks][nt], s[mt][nt]);
      __builtin_amdgcn_s_setprio(0);
    }
    if (last) {
#pragma unroll
      for (int nt = 0; nt < 4; ++nt)
        if (1024 + nt * 16 + l15 > NTOK - 1) {
#pragma unroll
          for (int mt = 0; mt < 2; ++mt)
#pragma unroll
            for (int j = 0; j < 4; ++j) s[mt][nt][j] = -1e30f;
        }
    }
    float smax[2][4];
    bool okl = true;
#pragma unroll
    for (int mt = 0; mt < 2; ++mt)
#pragma unroll
      for (int j = 0; j < 4; ++j) {
        const float a =
            fmaxf(fmaxf(s[mt][0][j], s[mt][1][j]), fmaxf(s[mt][2][j], s[mt][3][j]));
        smax[mt][j] = a;
        okl = okl && (a <= mrun[mt][j] + 8.0f);
      }
    if (!__all((int)okl)) {
#pragma unroll
      for (int mt = 0; mt < 2; ++mt)
#pragma unroll
        for (int j = 0; j < 4; ++j) {
          float m0 = smax[mt][j];
#pragma unroll
          for (int off = 1; off < 16; off <<= 1) m0 = fmaxf(m0, __shfl_xor(m0, off));
          const float mnew = fmaxf(mrun[mt][j], m0);
          const float fsc = exp2_raw(mrun[mt][j] - mnew);
          lpart[mt][j] *= fsc;
          mrun[mt][j] = mnew;
#pragma unroll
          for (int nd = 0; nd < 4; ++nd) accO[mt][nd][j] *= fsc;
        }
    }
#pragma unroll
    for (int mt = 0; mt < 2; ++mt)
#pragma unroll
      for (int j = 0; j < 4; ++j) {
        float acc = 0.0f;
        char* pw = Plc + pw_off[mt][j];
#pragma unroll
        for (int nt = 0; nt < 4; ++nt) {
          const float p = exp2_raw(s[mt][nt][j] - mrun[mt][j]);
          acc += p;
          *(__hip_bfloat16*)(pw + nt * 32) = cvt_bf16_raw(p);
        }
        lpart[mt][j] += acc;
      }
    bf16x8 pa[2][2], vf[2][4];
#pragma unroll
    for (int mt = 0; mt < 2; ++mt)
#pragma unroll
      for (int ks = 0; ks < 2; ++ks)
        pa[mt][ks] = *(const bf16x8*)(Plc + pa_off[mt][ks]);
    {
      const char* Vc = (const char*)&Vt[cur][0];
#pragma unroll
      for (int nd = 0; nd < 4; ++nd)
#pragma unroll
        for (int ks = 0; ks < 2; ++ks)
          vf[ks][nd] = *(const bf16x8*)(Vc + frag_off[ks][nd]);
    }
    __builtin_amdgcn_s_setprio(1);
#pragma unroll
    for (int mt = 0; mt < 2; ++mt)
#pragma unroll
      for (int nd = 0; nd < 4; ++nd)
#pragma unroll
        for (int ks = 0; ks < 2; ++ks)
          accO[mt][nd] = mfma_bf16(pa[mt][ks], vf[ks][nd], accO[mt][nd]);
    __builtin_amdgcn_s_setprio(0);
  };

  stageKV(0, 0);
  stageKV(1, 1);
  for (int kt = 0; kt < 17; ++kt) {
    if (kt < 16)
      wait_vmcnt<4>();
    else
      wait_vmcnt<0>();
    __builtin_amdgcn_s_barrier();
    if (kt + 2 < 17) stageKV(kt + 2, (kt + 2) % 3);
    step(kt, kt % 3, kt == 16);
  }

  const int b = bh / 12, h = bh - (bh / 12) * 12;
#pragma unroll
  for (int mt = 0; mt < 2; ++mt)
#pragma unroll
    for (int j = 0; j < 4; ++j) {
      float sum = lpart[mt][j];
#pragma unroll
      for (int off2 = 1; off2 < 16; off2 <<= 1) sum += __shfl_xor(sum, off2);
      const int t = qb + mt * 16 + q4 * 4 + j;
      if (t > NTOK - 1) continue;
      const float inv = 1.0f / sum;
      const size_t ro = ((size_t)(b * NTOK + t)) * 768 + h * 64;
#pragma unroll
      for (int nd = 0; nd < 4; ++nd) {
        const int d = nd * 16 + l15;
        ao[ro + d] = __float2bfloat16(accO[mt][nd][j] * inv);
      }
    }
}

extern "C" void kernel_launch(void* const* d_in, const int* in_sizes, int n_in,
                              void* d_out, int out_size, void* d_ws, size_t ws_size,
                              hipStream_t stream) {
  const float* x = (const float*)d_in[0];
  const float* sinp = (const float*)d_in[1];
  const float* cosp = (const float*)d_in[2];
  const float* qkvw = (const float*)d_in[3];
  const float* qkvb = (const float*)d_in[4];
  const float* projw = (const float*)d_in[5];
  const float* projb = (const float*)d_in[6];

  char* ws = (char*)d_ws;
  __hip_bfloat16* xhi = (__hip_bfloat16*)(ws + OFF_XHI);
  __hip_bfloat16* wqhi = (__hip_bfloat16*)(ws + OFF_WQHI);
  __hip_bfloat16* pwhi = (__hip_bfloat16*)(ws + OFF_PWHI);
  __hip_bfloat16* qb = (__hip_bfloat16*)(ws + OFF_Q);
  __hip_bfloat16* kb = (__hip_bfloat16*)(ws + OFF_K);
  __hip_bfloat16* vt = (__hip_bfloat16*)(ws + OFF_VT);
  __hip_bfloat16* ao = (__hip_bfloat16*)(ws + OFF_AO);

  // K0: fused prep (x cast + zero tail, qkv_w cast, proj_w cast, vT pad-zero)
  k_prep<<<N4_TOT / 256, 256, 0, stream>>>(x, qkvw, projw, xhi, wqhi, pwhi, vt);
  // K1: QKV GEMM (256x256, 8 waves, counted-vmcnt) + bias + RoPE
  // grid 297 = 9 cols x 33 row-panels, XCD-chunk remapped in-kernel
  k_gemm_qkv<9><<<dim3(9 * 33), 512, 0, stream>>>(xhi, wqhi, qkvb, sinp, cosp,
                                                  qb, kb, vt);
  // K2: flash attention -> attn_out bf16 (864 = 8 XCD * 12 heads * 9 qblocks)
  k_attn<<<dim3(864), 256, 0, stream>>>(qb, kb, vt, ao);
  // K3: proj GEMM (NT=2) + bias -> fp32 out
  // grid 396 = 6 cols x 66 row-panels, XCD-chunk remapped in-kernel
  k_gemm_proj<6><<<dim3(6 * 66), 256, 0, stream>>>(ao, pwhi, projb,
                                                   (float*)d_out);
}

// Round 18
// 204.400 us; speedup vs baseline: 1.1906x; 1.1906x over previous
//
#include <hip/hip_runtime.h>
#include <hip/hip_bf16.h>

// ===== Problem constants =====
// B=8, N=1025, C=768, H=12, HD=64
constexpr int NTOK   = 1025;
constexpr int M      = 8 * NTOK;      // 8200 tokens
constexpr int MP     = 8320;          // 65 * 128 padded rows
constexpr int KDIM   = 768;
constexpr int NQKV   = 2304;
constexpr int NKVPAD = 1088;          // 17*64 padded kv length for vT
constexpr float SCALEL2 = 0.125f * 1.44269504f; // 64^-0.5 * log2(e), folded into K

using bf16x8 = __attribute__((ext_vector_type(8))) short;
using f32x4  = __attribute__((ext_vector_type(4))) float;

__device__ __forceinline__ f32x4 mfma_bf16(bf16x8 a, bf16x8 b, f32x4 c) {
  return __builtin_amdgcn_mfma_f32_16x16x32_bf16(a, b, c, 0, 0, 0);
}

__device__ __forceinline__ void gl16(const void* g, void* l) {
  __builtin_amdgcn_global_load_lds(
      (const __attribute__((address_space(1))) void*)g,
      (__attribute__((address_space(3))) void*)l, 16, 0, 0);
}

// counted vmcnt wait (T4): never drain to 0 in the main loop
template <int N> __device__ __forceinline__ void wait_vmcnt() {
  if constexpr (N == 0)
    asm volatile("s_waitcnt vmcnt(0)" ::: "memory");
  else if constexpr (N == 4)
    asm volatile("s_waitcnt vmcnt(4)" ::: "memory");
  else if constexpr (N == 6)
    asm volatile("s_waitcnt vmcnt(6)" ::: "memory");
}

// raw 2^x (args bounded by defer-max <= 8; -1e30 masks flush to 0)
__device__ __forceinline__ float exp2_raw(float x) {
  float r;
  asm("v_exp_f32 %0, %1" : "=v"(r) : "v"(x));
  return r;
}
// hardware-RNE f32->bf16 (1 op vs ~5-op software RNE)
__device__ __forceinline__ unsigned short cvt_bf16_u16(float x) {
  unsigned u;
  asm("v_cvt_pk_bf16_f32 %0, %1, %2" : "=v"(u) : "v"(x), "v"(x));
  return (unsigned short)(u & 0xffffu);
}
__device__ __forceinline__ __hip_bfloat16 cvt_bf16_raw(float x) {
  union { unsigned short s; __hip_bfloat16 b; } c;
  c.s = cvt_bf16_u16(x);
  return c.b;
}

// ===== Workspace layout (bytes), all 256-aligned =====
constexpr size_t SZ_X     = (size_t)MP * KDIM * 2;        // 12,779,520
constexpr size_t SZ_WQ    = (size_t)NQKV * KDIM * 2;      // 3,538,944
constexpr size_t SZ_PW    = (size_t)KDIM * KDIM * 2;      // 1,179,648
constexpr size_t SZ_QK    = (size_t)96 * NTOK * 64 * 2;   // 12,595,200
constexpr size_t SZ_VT    = (size_t)96 * 64 * NKVPAD * 2; // 13,369,344
constexpr size_t OFF_XHI  = 0;
constexpr size_t OFF_WQHI = OFF_XHI + SZ_X;
constexpr size_t OFF_PWHI = OFF_WQHI + SZ_WQ;
constexpr size_t OFF_Q    = OFF_PWHI + SZ_PW;
constexpr size_t OFF_K    = OFF_Q + SZ_QK;
constexpr size_t OFF_VT   = OFF_K + SZ_QK;
constexpr size_t OFF_AO   = OFF_VT + SZ_VT;
// total ~69 MB

// ===== K0: fused prep — x->bf16 (zero tail), qkv_w->bf16, proj_w->bf16,
// vT pad-zero. One launch, float4/ushort4 vectorized. =====
constexpr int N4_X  = MP * KDIM / 4;          // 1,597,440
constexpr int N4_WQ = NQKV * KDIM / 4;        //   442,368
constexpr int N4_PW = KDIM * KDIM / 4;        //   147,456
constexpr int NPADC = NKVPAD - NTOK;          // 63
constexpr int N4_PAD = 96 * 64 * NPADC / 4;   //    96,768
constexpr int N4_TOT = N4_X + N4_WQ + N4_PW + N4_PAD; // 2,284,032 = 8922*256

__global__ void k_prep(const float* __restrict__ x, const float* __restrict__ qkvw,
                       const float* __restrict__ projw,
                       __hip_bfloat16* __restrict__ xhi,
                       __hip_bfloat16* __restrict__ wqhi,
                       __hip_bfloat16* __restrict__ pwhi,
                       __hip_bfloat16* __restrict__ vt) {
  const int u = blockIdx.x * 256 + threadIdx.x;
  if (u < N4_X) {
    const int i = u * 4;
    ushort4 o = {0, 0, 0, 0};
    if (i < M * KDIM) {
      const float4 v = *(const float4*)(x + i);
      o = ushort4{cvt_bf16_u16(v.x), cvt_bf16_u16(v.y), cvt_bf16_u16(v.z),
                  cvt_bf16_u16(v.w)};
    }
    *(ushort4*)((unsigned short*)xhi + i) = o;
  } else if (u < N4_X + N4_WQ) {
    const int i = (u - N4_X) * 4;
    const float4 v = *(const float4*)(qkvw + i);
    *(ushort4*)((unsigned short*)wqhi + i) = ushort4{
        cvt_bf16_u16(v.x), cvt_bf16_u16(v.y), cvt_bf16_u16(v.z), cvt_bf16_u16(v.w)};
  } else if (u < N4_X + N4_WQ + N4_PW) {
    const int i = (u - N4_X - N4_WQ) * 4;
    const float4 v = *(const float4*)(projw + i);
    *(ushort4*)((unsigned short*)pwhi + i) = ushort4{
        cvt_bf16_u16(v.x), cvt_bf16_u16(v.y), cvt_bf16_u16(v.z), cvt_bf16_u16(v.w)};
  } else {
    const int e0 = (u - N4_X - N4_WQ - N4_PW) * 4;
#pragma unroll
    for (int k = 0; k < 4; ++k) {
      const int e = e0 + k;
      const int r = e / NPADC;
      const int c = NTOK + (e - r * NPADC);
      vt[(size_t)r * NKVPAD + c] = __float2bfloat16(0.0f);
    }
  }
}

// ===== K1: QKV GEMM — 128x128 tile, BK=32, NT=2, counted-vmcnt 3-buf =====
// (R12's proven form: VGPR 84, LDS 48KB, ~2.9 blocks/CU; depth-2 prefetch,
// vmcnt(4) per step, raw barrier; plain bijective XCD-chunk remap.)
// LDS chunk-XOR swizzle -> conflict-free ds_read_b128 with linear gl16 dest.
// Epilogue: bias + RoPE -> q, k (pre-scaled by SCALEL2), vT.
template <int NBX>
__global__ __launch_bounds__(256) void k_gemm_qkv(
    const __hip_bfloat16* __restrict__ A, const __hip_bfloat16* __restrict__ B,
    const float* __restrict__ bias, const float* __restrict__ sinp,
    const float* __restrict__ cosp, __hip_bfloat16* __restrict__ o_q,
    __hip_bfloat16* __restrict__ o_k, __hip_bfloat16* __restrict__ o_vt) {
  const int tid = threadIdx.x;
  const int w = tid >> 6, lane = tid & 63;
  const int wm = w >> 1, wn = w & 1;
  const int l15 = lane & 15, q4 = lane >> 4;

  // bijective XCD-chunk remap
  const int nwg = gridDim.x;
  const int orig = blockIdx.x;
  const int qc = nwg >> 3, rc = nwg & 7;
  const int xcd = orig & 7, o8 = orig >> 3;
  const int wg =
      (xcd < rc ? xcd * (qc + 1) : rc * (qc + 1) + (xcd - rc) * qc) + o8;
  const int bx = wg % NBX, by = wg / NBX;
  const int mBase = by * 128, nBase = bx * 128;

  __shared__ __hip_bfloat16 sm[3][2 * 4096]; // 3 bufs x (A 8KB + B 8KB)
  constexpr int OFFB = 8192;                 // byte offset of B tile

  const char* p0 = (const char*)A + (size_t)mBase * (KDIM * 2);
  const char* p2 = (const char*)B + (size_t)nBase * (KDIM * 2);

  const int slog = ((tid & 3) ^ ((tid >> 3) & 3)) << 4; // staged slot byte offset
  const int ph = ((q4 ^ ((l15 >> 1) & 3)) << 4);        // fragment slot byte offset

  auto stage = [&](int kt, int buf) {
    const int kofs = kt * 64; // bytes into each row
    char* base = (char*)sm[buf];
#pragma unroll
    for (int i = 0; i < 2; ++i) {
      const int c = i * 256 + tid; // 16B chunk index, 512 per tile
      const size_t rb = (size_t)(i * 64 + (tid >> 2)) * (KDIM * 2) + slog + kofs;
      gl16(p0 + rb, base + (size_t)c * 16);
      gl16(p2 + rb, base + OFFB + (size_t)c * 16);
    }
  };

  f32x4 acc[4][4] = {};

  stage(0, 0);
  stage(1, 1); // depth-2 prologue: 8 loads/thread in flight

  constexpr int NKT = KDIM / 32; // 24
  for (int kt = 0; kt < NKT; ++kt) {
    if (kt < NKT - 1)
      wait_vmcnt<4>(); // tile kt landed; kt+1 stays in flight
    else
      wait_vmcnt<0>();
    __builtin_amdgcn_s_barrier();
    if (kt + 2 < NKT) stage(kt + 2, (kt + 2) % 3);
    char* s0 = (char*)sm[kt % 3];
    char* s2 = s0 + OFFB;
    bf16x8 a0[4], b0[4];
#pragma unroll
    for (int mt = 0; mt < 4; ++mt) {
      const int r = wm * 64 + mt * 16 + l15;
      a0[mt] = *(const bf16x8*)(s0 + r * 64 + ph);
    }
#pragma unroll
    for (int nt = 0; nt < 4; ++nt) {
      const int r = wn * 64 + nt * 16 + l15;
      b0[nt] = *(const bf16x8*)(s2 + r * 64 + ph);
    }
    __builtin_amdgcn_s_setprio(1);
#pragma unroll
    for (int mt = 0; mt < 4; ++mt)
#pragma unroll
      for (int nt = 0; nt < 4; ++nt)
        acc[mt][nt] = mfma_bf16(a0[mt], b0[nt], acc[mt][nt]);
    __builtin_amdgcn_s_setprio(0);
  }

  // epilogue; C layout: col = lane&15, row = 4*(lane>>4)+j
#pragma unroll
  for (int mt = 0; mt < 4; ++mt)
#pragma unroll
    for (int j = 0; j < 4; ++j) {
      const int gm = mBase + wm * 64 + mt * 16 + q4 * 4 + j;
      if (gm >= M) continue;
      const int b = gm / NTOK;
      const int t = gm - b * NTOK;
#pragma unroll
      for (int nt = 0; nt < 4; ++nt) {
        const int gc = nBase + wn * 64 + nt * 16 + l15;
        float v = acc[mt][nt][j] + bias[gc];
        const int three = gc / 768;
        const int hd = gc - three * 768;
        const int h = hd >> 6, d = hd & 63;
        const int bh = b * 12 + h;
        if (three == 2) {
          o_vt[((size_t)bh * 64 + d) * NKVPAD + t] = __float2bfloat16(v);
        } else {
          if (t > 0) {
            const float pv = acc[mt][nt ^ 2][j] + bias[gc ^ 32];
            const int so = (t - 1) * 64 + d;
            v = v * cosp[so] + ((d < 32) ? -pv : pv) * sinp[so];
          }
          if (three == 0)
            o_q[((size_t)bh * NTOK + t) * 64 + d] = __float2bfloat16(v);
          else  // K: fold softmax scale * log2(e) here
            o_k[((size_t)bh * NTOK + t) * 64 + d] = __float2bfloat16(v * SCALEL2);
        }
      }
    }
}

// ===== K3: proj GEMM — 128x128, BK=32, NT=2 (w hi only; w_lo term's
// contribution ~1e-3 absmax), counted-vmcnt 3-buf (R17's proven form). =====
template <int NBX>
__global__ __launch_bounds__(256) void k_gemm_proj(
    const __hip_bfloat16* __restrict__ Ain, const __hip_bfloat16* __restrict__ Bhi,
    const float* __restrict__ bias, float* __restrict__ o_f32) {
  const int tid = threadIdx.x;
  const int w = tid >> 6, lane = tid & 63;
  const int wm = w >> 1, wn = w & 1;
  const int l15 = lane & 15, q4 = lane >> 4;

  const int nwg = gridDim.x;
  const int orig = blockIdx.x;
  const int qc = nwg >> 3, rc = nwg & 7;
  const int xcd = orig & 7, o8 = orig >> 3;
  const int wg =
      (xcd < rc ? xcd * (qc + 1) : rc * (qc + 1) + (xcd - rc) * qc) + o8;
  const int bx = wg % NBX, by = wg / NBX;
  const int mBase = by * 128, nBase = bx * 128;

  __shared__ __hip_bfloat16 sm[3][2 * 4096]; // 3 bufs x (A 8KB + B 8KB)
  constexpr int OFFB = 8192;

  const char* p0 = (const char*)Ain + (size_t)mBase * (KDIM * 2);
  const char* p2 = (const char*)Bhi + (size_t)nBase * (KDIM * 2);

  const int slog = ((tid & 3) ^ ((tid >> 3) & 3)) << 4;
  const int ph = ((q4 ^ ((l15 >> 1) & 3)) << 4);

  auto stage = [&](int kt, int buf) {
    const int kofs = kt * 64;
    char* base = (char*)sm[buf];
#pragma unroll
    for (int i = 0; i < 2; ++i) {
      const int c = i * 256 + tid;
      const size_t rb = (size_t)(i * 64 + (tid >> 2)) * (KDIM * 2) + slog + kofs;
      gl16(p0 + rb, base + (size_t)c * 16);
      gl16(p2 + rb, base + OFFB + (size_t)c * 16);
    }
  };

  f32x4 acc[4][4] = {};

  stage(0, 0);
  stage(1, 1);

  constexpr int NKT = KDIM / 32; // 24
  for (int kt = 0; kt < NKT; ++kt) {
    if (kt < NKT - 1)
      wait_vmcnt<4>();
    else
      wait_vmcnt<0>();
    __builtin_amdgcn_s_barrier();
    if (kt + 2 < NKT) stage(kt + 2, (kt + 2) % 3);
    char* s0 = (char*)sm[kt % 3];
    char* s2 = s0 + OFFB;
    bf16x8 a0[4], b0[4];
#pragma unroll
    for (int mt = 0; mt < 4; ++mt) {
      const int r = wm * 64 + mt * 16 + l15;
      a0[mt] = *(const bf16x8*)(s0 + r * 64 + ph);
    }
#pragma unroll
    for (int nt = 0; nt < 4; ++nt) {
      const int r = wn * 64 + nt * 16 + l15;
      b0[nt] = *(const bf16x8*)(s2 + r * 64 + ph);
    }
    __builtin_amdgcn_s_setprio(1);
#pragma unroll
    for (int mt = 0; mt < 4; ++mt)
#pragma unroll
      for (int nt = 0; nt < 4; ++nt)
        acc[mt][nt] = mfma_bf16(a0[mt], b0[nt], acc[mt][nt]);
    __builtin_amdgcn_s_setprio(0);
  }

#pragma unroll
  for (int mt = 0; mt < 4; ++mt)
#pragma unroll
    for (int j = 0; j < 4; ++j) {
      const int gm = mBase + wm * 64 + mt * 16 + q4 * 4 + j;
      if (gm >= M) continue;
#pragma unroll
      for (int nt = 0; nt < 4; ++nt) {
        const int gc = nBase + wn * 64 + nt * 16 + l15;
        o_f32[(size_t)gm * 768 + gc] = acc[mt][nt][j] + bias[gc];
      }
    }
}

// ===== K2: flash attention, 4 waves x 32 q-rows, KV tiles of 64 =====
// (R12 form, unchanged.)
__global__ __launch_bounds__(256) void k_attn(
    const __hip_bfloat16* __restrict__ Q, const __hip_bfloat16* __restrict__ Kk,
    const __hip_bfloat16* __restrict__ VT, __hip_bfloat16* __restrict__ ao) {
  __shared__ __hip_bfloat16 Kt[3][64 * 64];
  __shared__ __hip_bfloat16 Vt[3][64 * 64];
  __shared__ __hip_bfloat16 Pl[4][32][72];
  const int tid = threadIdx.x, w = tid >> 6, lane = tid & 63;
  const int l15 = lane & 15, q4 = lane >> 4;
  const int id = blockIdx.x;
  const int xcd = id & 7, sub = id >> 3;
  const int hh = sub / 9;
  const int bh = xcd * 12 + hh;
  const int qb = (sub - hh * 9) * 128 + w * 32;
  const size_t qbase = (size_t)bh * NTOK * 64;
  const char* Kb = (const char*)(Kk + qbase);
  const char* Vb = (const char*)(VT + (size_t)bh * 64 * NKVPAD);

  int frag_off[2][4];
#pragma unroll
  for (int f = 0; f < 4; ++f) {
    const int row = f * 16 + l15;
#pragma unroll
    for (int ks = 0; ks < 2; ++ks)
      frag_off[ks][f] = row * 128 + (((ks * 4 + q4) ^ (row & 7)) << 4);
  }
  int stRow[2], sch16[2], stK[2], stV[2], ldsOff[2];
#pragma unroll
  for (int i = 0; i < 2; ++i) {
    const int c = i * 256 + tid;
    const int row = c >> 3;
    stRow[i] = row;
    sch16[i] = ((c & 7) ^ (row & 7)) << 4;
    stK[i] = row * 128 + sch16[i];
    stV[i] = row * (NKVPAD * 2) + sch16[i];
    ldsOff[i] = c * 16;
  }
  int pw_off[2][4], pa_off[2][2];
#pragma unroll
  for (int mt = 0; mt < 2; ++mt) {
#pragma unroll
    for (int j = 0; j < 4; ++j)
      pw_off[mt][j] = ((w * 32 + mt * 16 + q4 * 4 + j) * 72 + l15) * 2;
#pragma unroll
    for (int ks = 0; ks < 2; ++ks)
      pa_off[mt][ks] = ((w * 32 + mt * 16 + l15) * 72 + ks * 32 + q4 * 8) * 2;
  }
  char* Plc = (char*)&Pl[0][0][0];

  bf16x8 qa[2][2];
#pragma unroll
  for (int mt = 0; mt < 2; ++mt) {
    int t = qb + mt * 16 + l15;
    if (t > NTOK - 1) t = NTOK - 1;
#pragma unroll
    for (int ks = 0; ks < 2; ++ks)
      qa[mt][ks] = *(const bf16x8*)(Q + qbase + (size_t)t * 64 + ks * 32 + q4 * 8);
  }

  f32x4 accO[2][4] = {};
  float mrun[2][4], lpart[2][4];
#pragma unroll
  for (int mt = 0; mt < 2; ++mt)
#pragma unroll
    for (int j = 0; j < 4; ++j) {
      mrun[mt][j] = -1e30f;
      lpart[mt][j] = 0.0f;
    }

  auto stageKV = [&](int kt, int b) {
    const int kb0 = kt * 64;
#pragma unroll
    for (int i = 0; i < 2; ++i) {
      const char* srcK;
      if (kt == 16) {
        const int srow = min(kb0 + stRow[i], NTOK - 1);
        srcK = Kb + (size_t)srow * 128 + sch16[i];
      } else {
        srcK = Kb + (size_t)kb0 * 128 + stK[i];
      }
      gl16(srcK, (char*)&Kt[b][0] + ldsOff[i]);
      gl16(Vb + (size_t)kb0 * 2 + stV[i], (char*)&Vt[b][0] + ldsOff[i]);
    }
  };

  auto step = [&](int kt, int cur, bool last) {
    f32x4 s[2][4] = {};
    {
      const char* Kc = (const char*)&Kt[cur][0];
      bf16x8 kfr[2][4];
#pragma unroll
      for (int nt = 0; nt < 4; ++nt)
#pragma unroll
        for (int ks = 0; ks < 2; ++ks)
          kfr[ks][nt] = *(const bf16x8*)(Kc + frag_off[ks][nt]);
      __builtin_amdgcn_s_setprio(1);
#pragma unroll
      for (int mt = 0; mt < 2; ++mt)
#pragma unroll
        for (int nt = 0; nt < 4; ++nt)
#pragma unroll
          for (int ks = 0; ks < 2; ++ks)
            s[mt][nt] = mfma_bf16(qa[mt][ks], kfr[ks][nt], s[mt][nt]);
      __builtin_amdgcn_s_setprio(0);
    }
    if (last) {
#pragma unroll
      for (int nt = 0; nt < 4; ++nt)
        if (1024 + nt * 16 + l15 > NTOK - 1) {
#pragma unroll
          for (int mt = 0; mt < 2; ++mt)
#pragma unroll
            for (int j = 0; j < 4; ++j) s[mt][nt][j] = -1e30f;
        }
    }
    float smax[2][4];
    bool okl = true;
#pragma unroll
    for (int mt = 0; mt < 2; ++mt)
#pragma unroll
      for (int j = 0; j < 4; ++j) {
        const float a =
            fmaxf(fmaxf(s[mt][0][j], s[mt][1][j]), fmaxf(s[mt][2][j], s[mt][3][j]));
        smax[mt][j] = a;
        okl = okl && (a <= mrun[mt][j] + 8.0f);
      }
    if (!__all((int)okl)) {
#pragma unroll
      for (int mt = 0; mt < 2; ++mt)
#pragma unroll
        for (int j = 0; j < 4; ++j) {
          float m0 = smax[mt][j];
#pragma unroll
          for (int off = 1; off < 16; off <<= 1) m0 = fmaxf(m0, __shfl_xor(m0, off));
          const float mnew = fmaxf(mrun[mt][j], m0);
          const float fsc = exp2_raw(mrun[mt][j] - mnew);
          lpart[mt][j] *= fsc;
          mrun[mt][j] = mnew;
#pragma unroll
          for (int nd = 0; nd < 4; ++nd) accO[mt][nd][j] *= fsc;
        }
    }
#pragma unroll
    for (int mt = 0; mt < 2; ++mt)
#pragma unroll
      for (int j = 0; j < 4; ++j) {
        float acc = 0.0f;
        char* pw = Plc + pw_off[mt][j];
#pragma unroll
        for (int nt = 0; nt < 4; ++nt) {
          const float p = exp2_raw(s[mt][nt][j] - mrun[mt][j]);
          acc += p;
          *(__hip_bfloat16*)(pw + nt * 32) = cvt_bf16_raw(p);
        }
        lpart[mt][j] += acc;
      }
    bf16x8 pa[2][2], vf[2][4];
#pragma unroll
    for (int mt = 0; mt < 2; ++mt)
#pragma unroll
      for (int ks = 0; ks < 2; ++ks)
        pa[mt][ks] = *(const bf16x8*)(Plc + pa_off[mt][ks]);
    {
      const char* Vc = (const char*)&Vt[cur][0];
#pragma unroll
      for (int nd = 0; nd < 4; ++nd)
#pragma unroll
        for (int ks = 0; ks < 2; ++ks)
          vf[ks][nd] = *(const bf16x8*)(Vc + frag_off[ks][nd]);
    }
    __builtin_amdgcn_s_setprio(1);
#pragma unroll
    for (int mt = 0; mt < 2; ++mt)
#pragma unroll
      for (int nd = 0; nd < 4; ++nd)
#pragma unroll
        for (int ks = 0; ks < 2; ++ks)
          accO[mt][nd] = mfma_bf16(pa[mt][ks], vf[ks][nd], accO[mt][nd]);
    __builtin_amdgcn_s_setprio(0);
  };

  stageKV(0, 0);
  stageKV(1, 1);
  for (int kt = 0; kt < 17; ++kt) {
    if (kt < 16)
      wait_vmcnt<4>();
    else
      wait_vmcnt<0>();
    __builtin_amdgcn_s_barrier();
    if (kt + 2 < 17) stageKV(kt + 2, (kt + 2) % 3);
    step(kt, kt % 3, kt == 16);
  }

  const int b = bh / 12, h = bh - (bh / 12) * 12;
#pragma unroll
  for (int mt = 0; mt < 2; ++mt)
#pragma unroll
    for (int j = 0; j < 4; ++j) {
      float sum = lpart[mt][j];
#pragma unroll
      for (int off2 = 1; off2 < 16; off2 <<= 1) sum += __shfl_xor(sum, off2);
      const int t = qb + mt * 16 + q4 * 4 + j;
      if (t > NTOK - 1) continue;
      const float inv = 1.0f / sum;
      const size_t ro = ((size_t)(b * NTOK + t)) * 768 + h * 64;
#pragma unroll
      for (int nd = 0; nd < 4; ++nd) {
        const int d = nd * 16 + l15;
        ao[ro + d] = __float2bfloat16(accO[mt][nd][j] * inv);
      }
    }
}

extern "C" void kernel_launch(void* const* d_in, const int* in_sizes, int n_in,
                              void* d_out, int out_size, void* d_ws, size_t ws_size,
                              hipStream_t stream) {
  const float* x = (const float*)d_in[0];
  const float* sinp = (const float*)d_in[1];
  const float* cosp = (const float*)d_in[2];
  const float* qkvw = (const float*)d_in[3];
  const float* qkvb = (const float*)d_in[4];
  const float* projw = (const float*)d_in[5];
  const float* projb = (const float*)d_in[6];

  char* ws = (char*)d_ws;
  __hip_bfloat16* xhi = (__hip_bfloat16*)(ws + OFF_XHI);
  __hip_bfloat16* wqhi = (__hip_bfloat16*)(ws + OFF_WQHI);
  __hip_bfloat16* pwhi = (__hip_bfloat16*)(ws + OFF_PWHI);
  __hip_bfloat16* qb = (__hip_bfloat16*)(ws + OFF_Q);
  __hip_bfloat16* kb = (__hip_bfloat16*)(ws + OFF_K);
  __hip_bfloat16* vt = (__hip_bfloat16*)(ws + OFF_VT);
  __hip_bfloat16* ao = (__hip_bfloat16*)(ws + OFF_AO);

  // K0: fused prep (x cast + zero tail, qkv_w cast, proj_w cast, vT pad-zero)
  k_prep<<<N4_TOT / 256, 256, 0, stream>>>(x, qkvw, projw, xhi, wqhi, pwhi, vt);
  // K1: QKV GEMM (R12 proven form) + bias + RoPE -> q, k(scaled), vT
  // grid 1170 = 18 cols x 65 row-panels, XCD-chunk remapped in-kernel
  k_gemm_qkv<18><<<dim3(18 * 65), 256, 0, stream>>>(xhi, wqhi, qkvb, sinp, cosp,
                                                    qb, kb, vt);
  // K2: flash attention -> attn_out bf16 (864 = 8 XCD * 12 heads * 9 qblocks)
  k_attn<<<dim3(864), 256, 0, stream>>>(qb, kb, vt, ao);
  // K3: proj GEMM (NT=2) + bias -> fp32 out
  // grid 390 = 6 cols x 65 row-panels, XCD-chunk remapped in-kernel
  k_gemm_proj<6><<<dim3(6 * 65), 256, 0, stream>>>(ao, pwhi, projb,
                                                   (float*)d_out);
}